// Round 1
// baseline (4033.418 us; speedup 1.0000x reference)
//
#include <hip/hip_runtime.h>
#include <stdint.h>

#define Bb 2
#define Dd 16
#define Hh 64
#define Ww 64
#define NPOS 131072   // B*D*H*W
#define NACT 40000    // B*NV
#define NVb 20000
#define KFORE 10000
#define EPSf 0.001f

static __device__ __forceinline__ uint32_t f2sort(float f) {
    uint32_t u = __float_as_uint(f);
    return (u & 0x80000000u) ? ~u : (u | 0x80000000u);
}

// ---------------- scatter features to dense grid ----------------
__global__ void __launch_bounds__(256) k_scatter(const float* __restrict__ feat,
                                                 const int* __restrict__ coords,
                                                 float* __restrict__ dense16,
                                                 uint8_t* __restrict__ active,
                                                 uint8_t* __restrict__ new_act) {
    int i = blockIdx.x * 256 + threadIdx.x;
    if (i >= NACT) return;
    int b = coords[i * 4 + 0], z = coords[i * 4 + 1], y = coords[i * 4 + 2], x = coords[i * 4 + 3];
    int pos = ((b * Dd + z) * Hh + y) * Ww + x;
    active[pos] = 1;
    new_act[pos] = 1;
    const float4* f4 = (const float4*)(feat + (size_t)i * 16);
    float4* d4 = (float4*)(dense16 + (size_t)pos * 16);
    d4[0] = f4[0]; d4[1] = f4[1]; d4[2] = f4[2]; d4[3] = f4[3];
}

// ---------------- conv1 16->32 + BN + ReLU at active voxels ----------------
__global__ void __launch_bounds__(64) k_conv1(const int* __restrict__ coords,
                                              const float* __restrict__ dense16,
                                              const float* __restrict__ w1,
                                              const float* __restrict__ g, const float* __restrict__ bta,
                                              const float* __restrict__ mu, const float* __restrict__ va,
                                              float* __restrict__ h1, const float* __restrict__ zrow) {
    const int lane = threadIdx.x;
    const int v = lane >> 5, co = lane & 31;
    const int vi = blockIdx.x * 2 + v;
    const int* c = coords + (size_t)vi * 4;
    const int b = c[0], z = c[1], y = c[2], x = c[3];
    float acc = 0.f;
    #pragma unroll
    for (int t = 0; t < 27; ++t) {
        const int dz = t / 9 - 1, dy = (t / 3) % 3 - 1, dx = t % 3 - 1;
        int nz = z + dz, ny = y + dy, nx = x + dx;
        bool ok = (unsigned)nz < Dd && (unsigned)ny < Hh && (unsigned)nx < Ww;
        const float* inp = ok ? dense16 + (size_t)(((b * Dd + nz) * Hh + ny) * Ww + nx) * 16 : zrow;
        const float* wt = w1 + t * 16 * 32 + co;
        #pragma unroll
        for (int c4 = 0; c4 < 4; ++c4) {
            float4 xv = *(const float4*)(inp + c4 * 4);
            acc = fmaf(xv.x, wt[(c4 * 4 + 0) * 32], acc);
            acc = fmaf(xv.y, wt[(c4 * 4 + 1) * 32], acc);
            acc = fmaf(xv.z, wt[(c4 * 4 + 2) * 32], acc);
            acc = fmaf(xv.w, wt[(c4 * 4 + 3) * 32], acc);
        }
    }
    float s = g[co] * (1.0f / sqrtf(va[co] + EPSf));
    float o = fmaxf(0.f, fmaf(acc - mu[co], s, bta[co]));
    int pos = ((b * Dd + z) * Hh + y) * Ww + x;
    h1[(size_t)pos * 32 + co] = o;
}

// ---------------- conv2 32->64 + BN + ReLU at active voxels (4 voxels/block) ----------------
__global__ void __launch_bounds__(64) k_conv2(const int* __restrict__ coords,
                                              const float* __restrict__ h1,
                                              const float* __restrict__ w2,
                                              const float* __restrict__ g, const float* __restrict__ bta,
                                              const float* __restrict__ mu, const float* __restrict__ va,
                                              float* __restrict__ h2, const float* __restrict__ zrow) {
    const int co = threadIdx.x;
    const int vi0 = blockIdx.x * 4;
    int pb[4], pz[4], py[4], px[4];
    #pragma unroll
    for (int v = 0; v < 4; ++v) {
        const int* c = coords + (size_t)(vi0 + v) * 4;
        pb[v] = c[0]; pz[v] = c[1]; py[v] = c[2]; px[v] = c[3];
    }
    float acc[4] = {0.f, 0.f, 0.f, 0.f};
    for (int t = 0; t < 27; ++t) {
        const int dz = t / 9 - 1, dy = (t / 3) % 3 - 1, dx = t % 3 - 1;
        const float* inp[4];
        #pragma unroll
        for (int v = 0; v < 4; ++v) {
            int nz = pz[v] + dz, ny = py[v] + dy, nx = px[v] + dx;
            bool ok = (unsigned)nz < Dd && (unsigned)ny < Hh && (unsigned)nx < Ww;
            inp[v] = ok ? h1 + (size_t)(((pb[v] * Dd + nz) * Hh + ny) * Ww + nx) * 32 : zrow;
        }
        const float* wt = w2 + t * 32 * 64 + co;
        #pragma unroll
        for (int c4 = 0; c4 < 8; ++c4) {
            float w0 = wt[(c4 * 4 + 0) * 64], w1v = wt[(c4 * 4 + 1) * 64];
            float w2v = wt[(c4 * 4 + 2) * 64], w3v = wt[(c4 * 4 + 3) * 64];
            #pragma unroll
            for (int v = 0; v < 4; ++v) {
                float4 xv = *(const float4*)(inp[v] + c4 * 4);
                acc[v] = fmaf(xv.x, w0, acc[v]);
                acc[v] = fmaf(xv.y, w1v, acc[v]);
                acc[v] = fmaf(xv.z, w2v, acc[v]);
                acc[v] = fmaf(xv.w, w3v, acc[v]);
            }
        }
    }
    float s = g[co] * (1.0f / sqrtf(va[co] + EPSf));
    float sh = bta[co], m = mu[co];
    #pragma unroll
    for (int v = 0; v < 4; ++v) {
        int pos = ((pb[v] * Dd + pz[v]) * Hh + py[v]) * Ww + px[v];
        h2[(size_t)pos * 64 + co] = fmaxf(0.f, fmaf(acc[v] - m, s, sh));
    }
}

// ---------------- importance conv 64->27 at active voxels ----------------
__global__ void __launch_bounds__(64) k_imp(const int* __restrict__ coords,
                                            const float* __restrict__ h2,
                                            const float* __restrict__ wimp,
                                            uint32_t* __restrict__ u_logits,
                                            uint32_t* __restrict__ kbits,
                                            const float* __restrict__ zrow) {
    const int lane = threadIdx.x;
    const int half = lane >> 5, co = lane & 31;
    const int vi = blockIdx.x * 2 + half;
    const int* c = coords + (size_t)vi * 4;
    const int b = c[0], z = c[1], y = c[2], x = c[3];
    const bool act = co < 27;
    float acc = 0.f;
    for (int t = 0; t < 27; ++t) {
        const int dz = t / 9 - 1, dy = (t / 3) % 3 - 1, dx = t % 3 - 1;
        int nz = z + dz, ny = y + dy, nx = x + dx;
        bool ok = (unsigned)nz < Dd && (unsigned)ny < Hh && (unsigned)nx < Ww;
        const float* inp = ok ? h2 + (size_t)(((b * Dd + nz) * Hh + ny) * Ww + nx) * 64 : zrow;
        const float* wt = wimp + t * 64 * 27 + co;
        #pragma unroll
        for (int c4 = 0; c4 < 16; ++c4) {
            float4 xv = *(const float4*)(inp + c4 * 4);
            if (act) {
                acc = fmaf(xv.x, wt[(c4 * 4 + 0) * 27], acc);
                acc = fmaf(xv.y, wt[(c4 * 4 + 1) * 27], acc);
                acc = fmaf(xv.z, wt[(c4 * 4 + 2) * 27], acc);
                acc = fmaf(xv.w, wt[(c4 * 4 + 3) * 27], acc);
            }
        }
    }
    unsigned long long m = __ballot(act && co < 26 && acc >= 0.0f);
    if (co == 26) u_logits[vi] = f2sort(acc);
    if (lane == 0)  kbits[blockIdx.x * 2]     = (uint32_t)(m & 0x3FFFFFFull);
    if (lane == 32) kbits[blockIdx.x * 2 + 1] = (uint32_t)((m >> 32) & 0x3FFFFFFull);
}

// ---------------- exact kth-largest (radix select on sortable bits) ----------------
__global__ void __launch_bounds__(256) k_select(const uint32_t* __restrict__ u_all,
                                                uint32_t* __restrict__ kth_u) {
    const int b = blockIdx.x;
    const uint32_t* u = u_all + (size_t)b * NVb;
    __shared__ int hist[256];
    __shared__ int s_d, s_above;
    uint32_t prefix = 0;
    int K = KFORE;
    for (int p = 3; p >= 0; --p) {
        hist[threadIdx.x] = 0;
        __syncthreads();
        const int sh = p * 8;
        for (int i = threadIdx.x; i < NVb; i += 256) {
            uint32_t ui = u[i];
            bool cand;
            if (p == 3) cand = true;
            else cand = ((ui >> (sh + 8)) == prefix);
            if (cand) atomicAdd(&hist[(ui >> sh) & 255], 1);
        }
        __syncthreads();
        if (threadIdx.x == 0) {
            int cum = 0, d = 255;
            for (; d >= 0; --d) { cum += hist[d]; if (cum >= K) break; }
            s_d = d; s_above = cum - hist[d];
        }
        __syncthreads();
        prefix = (prefix << 8) | (uint32_t)s_d;
        K -= s_above;
        __syncthreads();
    }
    if (threadIdx.x == 0) kth_u[b] = prefix;
}

// ---------------- dilation (scatter fore voxels through kernel mask) ----------------
__global__ void __launch_bounds__(256) k_dilate(const int* __restrict__ coords,
                                                const uint32_t* __restrict__ u_logits,
                                                const uint32_t* __restrict__ kbits,
                                                const uint32_t* __restrict__ kth_u,
                                                uint8_t* __restrict__ new_act) {
    int i = blockIdx.x * 256 + threadIdx.x;
    if (i >= NACT) return;
    const int* c = coords + (size_t)i * 4;
    const int b = c[0], z = c[1], y = c[2], x = c[3];
    if (u_logits[i] < kth_u[b]) return;  // not fore
    uint32_t bits = kbits[i];
    while (bits) {
        int ch = __ffs(bits) - 1;
        bits &= bits - 1;
        int l = ch + (ch >= 13 ? 1 : 0);
        int oz = l / 9 - 1, oy = (l / 3) % 3 - 1, ox = l % 3 - 1;
        int tz = z + oz, ty = y + oy, tx = x + ox;
        // reference zeroes index-0 planes of the shifted mask
        if (tz >= 1 && tz < Dd && ty >= 1 && ty < Hh && tx >= 1 && tx < Ww)
            new_act[((b * Dd + tz) * Hh + ty) * Ww + tx] = 1;
    }
}

// ---------------- ordered compaction (deterministic, position-sorted) ----------------
__global__ void __launch_bounds__(1024) k_compact(const uint8_t* __restrict__ new_act,
                                                  int* __restrict__ list, int* __restrict__ count) {
    __shared__ int s[1024];
    const int tid = threadIdx.x;
    const int base = tid * 128;   // 1024*128 = 131072
    int c = 0;
    for (int j = 0; j < 128; ++j) c += new_act[base + j];
    s[tid] = c;
    __syncthreads();
    for (int off = 1; off < 1024; off <<= 1) {
        int v = s[tid];
        if (tid >= off) v += s[tid - off];
        __syncthreads();
        s[tid] = v;
        __syncthreads();
    }
    if (tid == 1023) *count = s[1023];
    int idx = s[tid] - c;  // exclusive prefix
    for (int j = 0; j < 128; ++j)
        if (new_act[base + j]) list[idx++] = base + j;
}

// ---------------- focal conv 64->128 + BN + ReLU at new_act voxels ----------------
// 1 wave/block, 16 voxels/block, each lane owns channels (lane, lane+64)
__global__ void __launch_bounds__(64) k_focal(const int* __restrict__ list,
                                              const int* __restrict__ count,
                                              const float* __restrict__ h2,
                                              const float* __restrict__ wf,
                                              const float* __restrict__ g, const float* __restrict__ bta,
                                              const float* __restrict__ mu, const float* __restrict__ va,
                                              float* __restrict__ out, const float* __restrict__ zrow) {
    const int n = *count;
    const int i0 = blockIdx.x * 16;
    if (i0 >= n) return;
    const int lane = threadIdx.x;
    int pos[16];
    #pragma unroll
    for (int v = 0; v < 16; ++v) {
        int idx = i0 + v;
        pos[v] = (idx < n) ? list[idx] : -1;
    }
    float acc0[16], acc1[16];
    #pragma unroll
    for (int v = 0; v < 16; ++v) { acc0[v] = 0.f; acc1[v] = 0.f; }
    for (int t = 0; t < 27; ++t) {
        const int dz = t / 9 - 1, dy = (t / 3) % 3 - 1, dx = t % 3 - 1;
        const float* inp[16];
        #pragma unroll
        for (int v = 0; v < 16; ++v) {
            int p = pos[v];
            int x = p & 63, y = (p >> 6) & 63, z = (p >> 12) & 15, b = p >> 16;
            int nz = z + dz, ny = y + dy, nx = x + dx;
            bool ok = (p >= 0) && (unsigned)nz < Dd && (unsigned)ny < Hh && (unsigned)nx < Ww;
            inp[v] = ok ? h2 + (size_t)(((b * Dd + nz) * Hh + ny) * Ww + nx) * 64 : zrow;
        }
        const float* wt = wf + t * 64 * 128 + lane;
        #pragma unroll
        for (int c4 = 0; c4 < 16; ++c4) {
            float wa0 = wt[(c4 * 4 + 0) * 128], wa1 = wt[(c4 * 4 + 1) * 128];
            float wa2 = wt[(c4 * 4 + 2) * 128], wa3 = wt[(c4 * 4 + 3) * 128];
            float wb0 = wt[(c4 * 4 + 0) * 128 + 64], wb1 = wt[(c4 * 4 + 1) * 128 + 64];
            float wb2 = wt[(c4 * 4 + 2) * 128 + 64], wb3 = wt[(c4 * 4 + 3) * 128 + 64];
            #pragma unroll
            for (int v = 0; v < 16; ++v) {
                float4 xv = *(const float4*)(inp[v] + c4 * 4);
                acc0[v] = fmaf(xv.x, wa0, acc0[v]);
                acc0[v] = fmaf(xv.y, wa1, acc0[v]);
                acc0[v] = fmaf(xv.z, wa2, acc0[v]);
                acc0[v] = fmaf(xv.w, wa3, acc0[v]);
                acc1[v] = fmaf(xv.x, wb0, acc1[v]);
                acc1[v] = fmaf(xv.y, wb1, acc1[v]);
                acc1[v] = fmaf(xv.z, wb2, acc1[v]);
                acc1[v] = fmaf(xv.w, wb3, acc1[v]);
            }
        }
    }
    float s0 = g[lane] * (1.0f / sqrtf(va[lane] + EPSf)), sh0 = bta[lane], m0 = mu[lane];
    float s1 = g[lane + 64] * (1.0f / sqrtf(va[lane + 64] + EPSf)), sh1 = bta[lane + 64], m1 = mu[lane + 64];
    #pragma unroll
    for (int v = 0; v < 16; ++v) {
        if (i0 + v < n) {
            float* o = out + (size_t)pos[v] * 128;
            o[lane]      = fmaxf(0.f, fmaf(acc0[v] - m0, s0, sh0));
            o[lane + 64] = fmaxf(0.f, fmaf(acc1[v] - m1, s1, sh1));
        }
    }
}

extern "C" void kernel_launch(void* const* d_in, const int* in_sizes, int n_in,
                              void* d_out, int out_size, void* d_ws, size_t ws_size,
                              hipStream_t stream) {
    (void)in_sizes; (void)n_in; (void)ws_size;
    const float* feat   = (const float*)d_in[0];
    const int*   coords = (const int*)d_in[1];
    const float* w1   = (const float*)d_in[2];
    const float* w2   = (const float*)d_in[3];
    const float* wimp = (const float*)d_in[4];
    const float* wf   = (const float*)d_in[5];
    const float* g1 = (const float*)d_in[6],  *b1 = (const float*)d_in[7];
    const float* m1 = (const float*)d_in[8],  *v1 = (const float*)d_in[9];
    const float* g2 = (const float*)d_in[10], *b2 = (const float*)d_in[11];
    const float* m2 = (const float*)d_in[12], *v2 = (const float*)d_in[13];
    const float* g3 = (const float*)d_in[14], *b3 = (const float*)d_in[15];
    const float* m3 = (const float*)d_in[16], *v3 = (const float*)d_in[17];

    char* ws = (char*)d_ws;
    float*    dense16  = (float*)(ws + 0);           //  8,388,608 B
    float*    h1       = (float*)(ws + 8388608);     // 16,777,216 B
    float*    h2       = (float*)(ws + 25165824);    // 33,554,432 B
    uint8_t*  active   = (uint8_t*)(ws + 58720256);  //    131,072 B
    uint8_t*  new_act  = (uint8_t*)(ws + 58851328);  //    131,072 B
    float*    zrow     = (float*)(ws + 58982400);    //        256 B (64 zero floats)
    int*      count    = (int*)(ws + 58982656);      //        256 B
    const size_t MEMSET_BYTES = 58982912;            // everything above zeroed per call
    uint32_t* u_logits = (uint32_t*)(ws + 58982912); //    160,000 B
    uint32_t* kbits    = (uint32_t*)(ws + 59142912); //    160,000 B
    uint32_t* kth_u    = (uint32_t*)(ws + 59302912); //        256 B
    int*      list     = (int*)(ws + 59303168);      //    524,288 B  -> total 59,827,456

    (void)active;
    hipMemsetAsync(d_ws, 0, MEMSET_BYTES, stream);
    hipMemsetAsync(d_out, 0, (size_t)out_size * sizeof(float), stream);

    k_scatter<<<157, 256, 0, stream>>>(feat, coords, dense16, active, new_act);
    k_conv1<<<20000, 64, 0, stream>>>(coords, dense16, w1, g1, b1, m1, v1, h1, zrow);
    k_conv2<<<10000, 64, 0, stream>>>(coords, h1, w2, g2, b2, m2, v2, h2, zrow);
    k_imp<<<20000, 64, 0, stream>>>(coords, h2, wimp, u_logits, kbits, zrow);
    k_select<<<2, 256, 0, stream>>>(u_logits, kth_u);
    k_dilate<<<157, 256, 0, stream>>>(coords, u_logits, kbits, kth_u, new_act);
    k_compact<<<1, 1024, 0, stream>>>(new_act, list, count);
    k_focal<<<8192, 64, 0, stream>>>(list, count, h2, wf, g3, b3, m3, v3, (float*)d_out, zrow);
}

// Round 2
// 2674.392 us; speedup vs baseline: 1.5082x; 1.5082x over previous
//
#include <hip/hip_runtime.h>
#include <stdint.h>

#define Dd 16
#define Hh 64
#define Ww 64
#define NACT 40000
#define NVb 20000
#define KFORE 10000
#define EPSf 0.001f

static __device__ __forceinline__ uint32_t f2sort(float f) {
    uint32_t u = __float_as_uint(f);
    return (u & 0x80000000u) ? ~u : (u | 0x80000000u);
}

// bijective XCD-contiguous remap (m204): chunk of ~nwg/8 consecutive logical
// blocks per XCD so spatially-adjacent blocks share one L2.
static __device__ __forceinline__ int xcd_swz(int orig, int nwg) {
    int xcd = orig & 7, idx = orig >> 3;
    int q = nwg >> 3, r = nwg & 7;
    int base = xcd < r ? xcd * (q + 1) : r * (q + 1) + (xcd - r) * q;
    return base + idx;
}

// ---------------- scatter features to dense grid ----------------
__global__ void __launch_bounds__(256) k_scatter(const float* __restrict__ feat,
                                                 const int* __restrict__ coords,
                                                 float* __restrict__ dense16,
                                                 uint8_t* __restrict__ active,
                                                 uint8_t* __restrict__ new_act) {
    int i = blockIdx.x * 256 + threadIdx.x;
    if (i >= NACT) return;
    int b = coords[i * 4 + 0], z = coords[i * 4 + 1], y = coords[i * 4 + 2], x = coords[i * 4 + 3];
    int pos = ((b * Dd + z) * Hh + y) * Ww + x;
    active[pos] = 1;
    new_act[pos] = 1;
    const float4* f4 = (const float4*)(feat + (size_t)i * 16);
    float4* d4 = (float4*)(dense16 + (size_t)pos * 16);
    d4[0] = f4[0]; d4[1] = f4[1]; d4[2] = f4[2]; d4[3] = f4[3];
}

// ---------------- ordered compaction (position-sorted list) ----------------
__global__ void __launch_bounds__(1024) k_compact(const uint8_t* __restrict__ mask,
                                                  int* __restrict__ list, int* __restrict__ count) {
    __shared__ int s[1024];
    const int tid = threadIdx.x;
    const int base = tid * 128;   // 1024*128 = 131072
    int c = 0;
    for (int j = 0; j < 128; ++j) c += mask[base + j];
    s[tid] = c;
    __syncthreads();
    for (int off = 1; off < 1024; off <<= 1) {
        int v = s[tid];
        if (tid >= off) v += s[tid - off];
        __syncthreads();
        s[tid] = v;
        __syncthreads();
    }
    if (tid == 1023) *count = s[1023];
    int idx = s[tid] - c;  // exclusive prefix
    for (int j = 0; j < 128; ++j)
        if (mask[base + j]) list[idx++] = base + j;
}

// ---------------- conv1 16->32 + BN + ReLU, ordered list, 2-voxel blocking ----------------
__global__ void __launch_bounds__(256, 4) k_conv1(const int* __restrict__ list,
        const float* __restrict__ dense16, const float* __restrict__ w1,
        const float* __restrict__ g, const float* __restrict__ bta,
        const float* __restrict__ mu, const float* __restrict__ va,
        float* __restrict__ h1, const float* __restrict__ zrow) {
    const int blk = xcd_swz(blockIdx.x, 2500);
    const int co = threadIdx.x & 31, vs = threadIdx.x >> 5;
    const int li = blk * 16 + vs * 2;
    const int p0 = list[li], p1 = list[li + 1];
    const int z0 = (p0 >> 12) & 15, y0 = (p0 >> 6) & 63, x0 = p0 & 63;
    const int z1 = (p1 >> 12) & 15, y1 = (p1 >> 6) & 63, x1 = p1 & 63;
    float acc0 = 0.f, acc1 = 0.f;
    #pragma unroll 3
    for (int t = 0; t < 27; ++t) {
        const int dz = t / 9 - 1, dy = (t / 3) % 3 - 1, dx = t % 3 - 1;
        const int off = dz * 4096 + dy * 64 + dx;
        bool ok0 = (unsigned)(z0 + dz) < Dd && (unsigned)(y0 + dy) < Hh && (unsigned)(x0 + dx) < Ww;
        bool ok1 = (unsigned)(z1 + dz) < Dd && (unsigned)(y1 + dy) < Hh && (unsigned)(x1 + dx) < Ww;
        const float* i0 = ok0 ? dense16 + (size_t)(p0 + off) * 16 : zrow;
        const float* i1 = ok1 ? dense16 + (size_t)(p1 + off) * 16 : zrow;
        const float* wt = w1 + t * 512 + co;
        #pragma unroll
        for (int c4 = 0; c4 < 4; ++c4) {
            float4 a0 = *(const float4*)(i0 + c4 * 4);
            float4 a1 = *(const float4*)(i1 + c4 * 4);
            float w0 = wt[(c4 * 4 + 0) * 32], w1v = wt[(c4 * 4 + 1) * 32];
            float w2v = wt[(c4 * 4 + 2) * 32], w3v = wt[(c4 * 4 + 3) * 32];
            acc0 = fmaf(a0.x, w0, acc0);  acc1 = fmaf(a1.x, w0, acc1);
            acc0 = fmaf(a0.y, w1v, acc0); acc1 = fmaf(a1.y, w1v, acc1);
            acc0 = fmaf(a0.z, w2v, acc0); acc1 = fmaf(a1.z, w2v, acc1);
            acc0 = fmaf(a0.w, w3v, acc0); acc1 = fmaf(a1.w, w3v, acc1);
        }
    }
    const float s = g[co] * (1.0f / sqrtf(va[co] + EPSf));
    const float sh = bta[co], m = mu[co];
    h1[(size_t)p0 * 32 + co] = fmaxf(0.f, fmaf(acc0 - m, s, sh));
    h1[(size_t)p1 * 32 + co] = fmaxf(0.f, fmaf(acc1 - m, s, sh));
}

// ---------------- conv2 32->64 + BN + ReLU, ordered list, 2-voxel blocking ----------------
__global__ void __launch_bounds__(256, 4) k_conv2(const int* __restrict__ list,
        const float* __restrict__ h1, const float* __restrict__ w2,
        const float* __restrict__ g, const float* __restrict__ bta,
        const float* __restrict__ mu, const float* __restrict__ va,
        float* __restrict__ h2, const float* __restrict__ zrow) {
    const int blk = xcd_swz(blockIdx.x, 5000);
    const int co = threadIdx.x & 63, vs = threadIdx.x >> 6;
    const int li = blk * 8 + vs * 2;
    const int p0 = list[li], p1 = list[li + 1];
    const int z0 = (p0 >> 12) & 15, y0 = (p0 >> 6) & 63, x0 = p0 & 63;
    const int z1 = (p1 >> 12) & 15, y1 = (p1 >> 6) & 63, x1 = p1 & 63;
    float acc0 = 0.f, acc1 = 0.f;
    #pragma unroll 3
    for (int t = 0; t < 27; ++t) {
        const int dz = t / 9 - 1, dy = (t / 3) % 3 - 1, dx = t % 3 - 1;
        const int off = dz * 4096 + dy * 64 + dx;
        bool ok0 = (unsigned)(z0 + dz) < Dd && (unsigned)(y0 + dy) < Hh && (unsigned)(x0 + dx) < Ww;
        bool ok1 = (unsigned)(z1 + dz) < Dd && (unsigned)(y1 + dy) < Hh && (unsigned)(x1 + dx) < Ww;
        const float* i0 = ok0 ? h1 + (size_t)(p0 + off) * 32 : zrow;
        const float* i1 = ok1 ? h1 + (size_t)(p1 + off) * 32 : zrow;
        const float* wt = w2 + t * 2048 + co;
        #pragma unroll
        for (int c4 = 0; c4 < 8; ++c4) {
            float4 a0 = *(const float4*)(i0 + c4 * 4);
            float4 a1 = *(const float4*)(i1 + c4 * 4);
            float w0 = wt[(c4 * 4 + 0) * 64], w1v = wt[(c4 * 4 + 1) * 64];
            float w2v = wt[(c4 * 4 + 2) * 64], w3v = wt[(c4 * 4 + 3) * 64];
            acc0 = fmaf(a0.x, w0, acc0);  acc1 = fmaf(a1.x, w0, acc1);
            acc0 = fmaf(a0.y, w1v, acc0); acc1 = fmaf(a1.y, w1v, acc1);
            acc0 = fmaf(a0.z, w2v, acc0); acc1 = fmaf(a1.z, w2v, acc1);
            acc0 = fmaf(a0.w, w3v, acc0); acc1 = fmaf(a1.w, w3v, acc1);
        }
    }
    const float s = g[co] * (1.0f / sqrtf(va[co] + EPSf));
    const float sh = bta[co], m = mu[co];
    h2[(size_t)p0 * 64 + co] = fmaxf(0.f, fmaf(acc0 - m, s, sh));
    h2[(size_t)p1 * 64 + co] = fmaxf(0.f, fmaf(acc1 - m, s, sh));
}

// ---------------- importance conv 64->27, ordered list, 2-voxel blocking ----------------
__global__ void __launch_bounds__(256, 4) k_imp(const int* __restrict__ list,
        const float* __restrict__ h2, const float* __restrict__ wimp,
        uint32_t* __restrict__ u_logits, uint32_t* __restrict__ kbits,
        const float* __restrict__ zrow) {
    const int blk = xcd_swz(blockIdx.x, 2500);
    const int lane = threadIdx.x & 63;
    const int co = threadIdx.x & 31, vs = threadIdx.x >> 5;
    const int coe = co < 27 ? co : 0;   // lanes 27..31 compute garbage, excluded below
    const int li = blk * 16 + vs * 2;
    const int p0 = list[li], p1 = list[li + 1];
    const int z0 = (p0 >> 12) & 15, y0 = (p0 >> 6) & 63, x0 = p0 & 63;
    const int z1 = (p1 >> 12) & 15, y1 = (p1 >> 6) & 63, x1 = p1 & 63;
    float acc0 = 0.f, acc1 = 0.f;
    #pragma unroll 3
    for (int t = 0; t < 27; ++t) {
        const int dz = t / 9 - 1, dy = (t / 3) % 3 - 1, dx = t % 3 - 1;
        const int off = dz * 4096 + dy * 64 + dx;
        bool ok0 = (unsigned)(z0 + dz) < Dd && (unsigned)(y0 + dy) < Hh && (unsigned)(x0 + dx) < Ww;
        bool ok1 = (unsigned)(z1 + dz) < Dd && (unsigned)(y1 + dy) < Hh && (unsigned)(x1 + dx) < Ww;
        const float* i0 = ok0 ? h2 + (size_t)(p0 + off) * 64 : zrow;
        const float* i1 = ok1 ? h2 + (size_t)(p1 + off) * 64 : zrow;
        const float* wt = wimp + t * 1728 + coe;
        #pragma unroll
        for (int c4 = 0; c4 < 16; ++c4) {
            float4 a0 = *(const float4*)(i0 + c4 * 4);
            float4 a1 = *(const float4*)(i1 + c4 * 4);
            float w0 = wt[(c4 * 4 + 0) * 27], w1v = wt[(c4 * 4 + 1) * 27];
            float w2v = wt[(c4 * 4 + 2) * 27], w3v = wt[(c4 * 4 + 3) * 27];
            acc0 = fmaf(a0.x, w0, acc0);  acc1 = fmaf(a1.x, w0, acc1);
            acc0 = fmaf(a0.y, w1v, acc0); acc1 = fmaf(a1.y, w1v, acc1);
            acc0 = fmaf(a0.z, w2v, acc0); acc1 = fmaf(a1.z, w2v, acc1);
            acc0 = fmaf(a0.w, w3v, acc0); acc1 = fmaf(a1.w, w3v, acc1);
        }
    }
    unsigned long long mb0 = __ballot(co < 26 && acc0 >= 0.0f);
    unsigned long long mb1 = __ballot(co < 26 && acc1 >= 0.0f);
    if ((lane & 31) == 0) {
        kbits[li]     = (uint32_t)(mb0 >> (lane & 32)) & 0x3FFFFFFu;
        kbits[li + 1] = (uint32_t)(mb1 >> (lane & 32)) & 0x3FFFFFFu;
    }
    if (co == 26) {
        u_logits[li]     = f2sort(acc0);
        u_logits[li + 1] = f2sort(acc1);
    }
}

// ---------------- exact kth-largest (radix select on sortable bits) ----------------
__global__ void __launch_bounds__(256) k_select(const uint32_t* __restrict__ u_all,
                                                uint32_t* __restrict__ kth_u) {
    const int b = blockIdx.x;
    const uint32_t* u = u_all + (size_t)b * NVb;
    __shared__ int hist[256];
    __shared__ int s_d, s_above;
    uint32_t prefix = 0;
    int K = KFORE;
    for (int p = 3; p >= 0; --p) {
        hist[threadIdx.x] = 0;
        __syncthreads();
        const int sh = p * 8;
        for (int i = threadIdx.x; i < NVb; i += 256) {
            uint32_t ui = u[i];
            bool cand;
            if (p == 3) cand = true;
            else cand = ((ui >> (sh + 8)) == prefix);
            if (cand) atomicAdd(&hist[(ui >> sh) & 255], 1);
        }
        __syncthreads();
        if (threadIdx.x == 0) {
            int cum = 0, d = 255;
            for (; d >= 0; --d) { cum += hist[d]; if (cum >= K) break; }
            s_d = d; s_above = cum - hist[d];
        }
        __syncthreads();
        prefix = (prefix << 8) | (uint32_t)s_d;
        K -= s_above;
        __syncthreads();
    }
    if (threadIdx.x == 0) kth_u[b] = prefix;
}

// ---------------- dilation ----------------
__global__ void __launch_bounds__(256) k_dilate(const int* __restrict__ list,
                                                const uint32_t* __restrict__ u_logits,
                                                const uint32_t* __restrict__ kbits,
                                                const uint32_t* __restrict__ kth_u,
                                                uint8_t* __restrict__ new_act) {
    int i = blockIdx.x * 256 + threadIdx.x;
    if (i >= NACT) return;
    int pos = list[i];
    int b = pos >> 16;
    if (u_logits[i] < kth_u[b]) return;  // not fore
    int z = (pos >> 12) & 15, y = (pos >> 6) & 63, x = pos & 63;
    uint32_t bits = kbits[i];
    while (bits) {
        int ch = __ffs(bits) - 1;
        bits &= bits - 1;
        int l = ch + (ch >= 13 ? 1 : 0);
        int oz = l / 9 - 1, oy = (l / 3) % 3 - 1, ox = l % 3 - 1;
        int tz = z + oz, ty = y + oy, tx = x + ox;
        // reference zeroes index-0 planes of the shifted mask
        if (tz >= 1 && tz < Dd && ty >= 1 && ty < Hh && tx >= 1 && tx < Ww)
            new_act[((b * Dd + tz) * Hh + ty) * Ww + tx] = 1;
    }
}

// ---------------- focal conv 64->128 + BN + ReLU at new_act voxels ----------------
// 1 wave/block, 16 voxels/block, each lane owns channels (lane, lane+64)
__global__ void __launch_bounds__(64) k_focal(const int* __restrict__ list,
                                              const int* __restrict__ count,
                                              const float* __restrict__ h2,
                                              const float* __restrict__ wf,
                                              const float* __restrict__ g, const float* __restrict__ bta,
                                              const float* __restrict__ mu, const float* __restrict__ va,
                                              float* __restrict__ out, const float* __restrict__ zrow) {
    const int n = *count;
    const int blk = xcd_swz(blockIdx.x, 8192);
    const int i0 = blk * 16;
    if (i0 >= n) return;
    const int lane = threadIdx.x;
    int pos[16];
    #pragma unroll
    for (int v = 0; v < 16; ++v) {
        int idx = i0 + v;
        pos[v] = (idx < n) ? list[idx] : -1;
    }
    float acc0[16], acc1[16];
    #pragma unroll
    for (int v = 0; v < 16; ++v) { acc0[v] = 0.f; acc1[v] = 0.f; }
    for (int t = 0; t < 27; ++t) {
        const int dz = t / 9 - 1, dy = (t / 3) % 3 - 1, dx = t % 3 - 1;
        const float* inp[16];
        #pragma unroll
        for (int v = 0; v < 16; ++v) {
            int p = pos[v];
            int x = p & 63, y = (p >> 6) & 63, z = (p >> 12) & 15, b = p >> 16;
            int nz = z + dz, ny = y + dy, nx = x + dx;
            bool ok = (p >= 0) && (unsigned)nz < Dd && (unsigned)ny < Hh && (unsigned)nx < Ww;
            inp[v] = ok ? h2 + (size_t)(((b * Dd + nz) * Hh + ny) * Ww + nx) * 64 : zrow;
        }
        const float* wt = wf + t * 64 * 128 + lane;
        #pragma unroll
        for (int c4 = 0; c4 < 16; ++c4) {
            float wa0 = wt[(c4 * 4 + 0) * 128], wa1 = wt[(c4 * 4 + 1) * 128];
            float wa2 = wt[(c4 * 4 + 2) * 128], wa3 = wt[(c4 * 4 + 3) * 128];
            float wb0 = wt[(c4 * 4 + 0) * 128 + 64], wb1 = wt[(c4 * 4 + 1) * 128 + 64];
            float wb2 = wt[(c4 * 4 + 2) * 128 + 64], wb3 = wt[(c4 * 4 + 3) * 128 + 64];
            #pragma unroll
            for (int v = 0; v < 16; ++v) {
                float4 xv = *(const float4*)(inp[v] + c4 * 4);
                acc0[v] = fmaf(xv.x, wa0, acc0[v]);
                acc0[v] = fmaf(xv.y, wa1, acc0[v]);
                acc0[v] = fmaf(xv.z, wa2, acc0[v]);
                acc0[v] = fmaf(xv.w, wa3, acc0[v]);
                acc1[v] = fmaf(xv.x, wb0, acc1[v]);
                acc1[v] = fmaf(xv.y, wb1, acc1[v]);
                acc1[v] = fmaf(xv.z, wb2, acc1[v]);
                acc1[v] = fmaf(xv.w, wb3, acc1[v]);
            }
        }
    }
    float s0 = g[lane] * (1.0f / sqrtf(va[lane] + EPSf)), sh0 = bta[lane], m0 = mu[lane];
    float s1 = g[lane + 64] * (1.0f / sqrtf(va[lane + 64] + EPSf)), sh1 = bta[lane + 64], m1 = mu[lane + 64];
    #pragma unroll
    for (int v = 0; v < 16; ++v) {
        if (i0 + v < n) {
            float* o = out + (size_t)pos[v] * 128;
            o[lane]      = fmaxf(0.f, fmaf(acc0[v] - m0, s0, sh0));
            o[lane + 64] = fmaxf(0.f, fmaf(acc1[v] - m1, s1, sh1));
        }
    }
}

extern "C" void kernel_launch(void* const* d_in, const int* in_sizes, int n_in,
                              void* d_out, int out_size, void* d_ws, size_t ws_size,
                              hipStream_t stream) {
    (void)in_sizes; (void)n_in; (void)ws_size;
    const float* feat   = (const float*)d_in[0];
    const int*   coords = (const int*)d_in[1];
    const float* w1   = (const float*)d_in[2];
    const float* w2   = (const float*)d_in[3];
    const float* wimp = (const float*)d_in[4];
    const float* wf   = (const float*)d_in[5];
    const float* g1 = (const float*)d_in[6],  *b1 = (const float*)d_in[7];
    const float* m1 = (const float*)d_in[8],  *v1 = (const float*)d_in[9];
    const float* g2 = (const float*)d_in[10], *b2 = (const float*)d_in[11];
    const float* m2 = (const float*)d_in[12], *v2 = (const float*)d_in[13];
    const float* g3 = (const float*)d_in[14], *b3 = (const float*)d_in[15];
    const float* m3 = (const float*)d_in[16], *v3 = (const float*)d_in[17];

    char* ws = (char*)d_ws;
    float*    dense16  = (float*)(ws + 0);           //  8,388,608 B
    float*    h1       = (float*)(ws + 8388608);     // 16,777,216 B
    float*    h2       = (float*)(ws + 25165824);    // 33,554,432 B
    uint8_t*  active   = (uint8_t*)(ws + 58720256);  //    131,072 B
    uint8_t*  new_act  = (uint8_t*)(ws + 58851328);  //    131,072 B
    float*    zrow     = (float*)(ws + 58982400);    //        256 B (64 zero floats)
    int*      count    = (int*)(ws + 58982656);      //        256 B
    const size_t MEMSET_BYTES = 58982912;            // everything above zeroed per call
    uint32_t* u_logits = (uint32_t*)(ws + 58982912); //    160,000 B
    uint32_t* kbits    = (uint32_t*)(ws + 59142912); //    160,000 B
    uint32_t* kth_u    = (uint32_t*)(ws + 59302912); //        256 B
    int*      list     = (int*)(ws + 59303168);      //    524,288 B (act list, then focal list)

    hipMemsetAsync(d_ws, 0, MEMSET_BYTES, stream);
    hipMemsetAsync(d_out, 0, (size_t)out_size * sizeof(float), stream);

    k_scatter<<<157, 256, 0, stream>>>(feat, coords, dense16, active, new_act);
    k_compact<<<1, 1024, 0, stream>>>(active, list, count);          // ordered active list (40000)
    k_conv1<<<2500, 256, 0, stream>>>(list, dense16, w1, g1, b1, m1, v1, h1, zrow);
    k_conv2<<<5000, 256, 0, stream>>>(list, h1, w2, g2, b2, m2, v2, h2, zrow);
    k_imp<<<2500, 256, 0, stream>>>(list, h2, wimp, u_logits, kbits, zrow);
    k_select<<<2, 256, 0, stream>>>(u_logits, kth_u);
    k_dilate<<<157, 256, 0, stream>>>(list, u_logits, kbits, kth_u, new_act);
    k_compact<<<1, 1024, 0, stream>>>(new_act, list, count);         // focal list (overwrites act list)
    k_focal<<<8192, 64, 0, stream>>>(list, count, h2, wf, g3, b3, m3, v3, (float*)d_out, zrow);
}

// Round 3
// 1550.515 us; speedup vs baseline: 2.6013x; 1.7248x over previous
//
#include <hip/hip_runtime.h>
#include <stdint.h>

#define Dd 16
#define Hh 64
#define Ww 64
#define NACT 40000
#define NVb 20000
#define KFORE 10000
#define EPSf 0.001f

typedef __attribute__((ext_vector_type(8))) short short8;   // 8 bf16 (4 VGPR)
typedef __attribute__((ext_vector_type(4))) float f32x4;
typedef __attribute__((ext_vector_type(4))) unsigned short us4;

static __device__ __forceinline__ uint32_t f2sort(float f) {
    uint32_t u = __float_as_uint(f);
    return (u & 0x80000000u) ? ~u : (u | 0x80000000u);
}

// round-to-nearest-even f32 -> bf16 bits (inputs finite)
static __device__ __forceinline__ unsigned short f2b(float f) {
    uint32_t u = __float_as_uint(f);
    return (unsigned short)((u + 0x7FFFu + ((u >> 16) & 1u)) >> 16);
}

// bijective XCD-contiguous remap (m204)
static __device__ __forceinline__ int xcd_swz(int orig, int nwg) {
    int xcd = orig & 7, idx = orig >> 3;
    int q = nwg >> 3, r = nwg & 7;
    int base = xcd < r ? xcd * (q + 1) : r * (q + 1) + (xcd - r) * q;
    return base + idx;
}

// ---------------- scatter features to dense grid ----------------
__global__ void __launch_bounds__(256) k_scatter(const float* __restrict__ feat,
                                                 const int* __restrict__ coords,
                                                 float* __restrict__ dense16,
                                                 uint8_t* __restrict__ active,
                                                 uint8_t* __restrict__ new_act) {
    int i = blockIdx.x * 256 + threadIdx.x;
    if (i >= NACT) return;
    int b = coords[i * 4 + 0], z = coords[i * 4 + 1], y = coords[i * 4 + 2], x = coords[i * 4 + 3];
    int pos = ((b * Dd + z) * Hh + y) * Ww + x;
    active[pos] = 1;
    new_act[pos] = 1;
    const float4* f4 = (const float4*)(feat + (size_t)i * 16);
    float4* d4 = (float4*)(dense16 + (size_t)pos * 16);
    d4[0] = f4[0]; d4[1] = f4[1]; d4[2] = f4[2]; d4[3] = f4[3];
}

// ---------------- ordered compaction (position-sorted list) ----------------
__global__ void __launch_bounds__(1024) k_compact(const uint8_t* __restrict__ mask,
                                                  int* __restrict__ list, int* __restrict__ count) {
    __shared__ int s[1024];
    const int tid = threadIdx.x;
    const int base = tid * 128;
    int c = 0;
    for (int j = 0; j < 128; ++j) c += mask[base + j];
    s[tid] = c;
    __syncthreads();
    for (int off = 1; off < 1024; off <<= 1) {
        int v = s[tid];
        if (tid >= off) v += s[tid - off];
        __syncthreads();
        s[tid] = v;
        __syncthreads();
    }
    if (tid == 1023) *count = s[1023];
    int idx = s[tid] - c;
    for (int j = 0; j < 128; ++j)
        if (mask[base + j]) list[idx++] = base + j;
}

// ---------------- conv1 16->32 + BN + ReLU ----------------
__global__ void __launch_bounds__(256, 4) k_conv1(const int* __restrict__ list,
        const float* __restrict__ dense16, const float* __restrict__ w1,
        const float* __restrict__ g, const float* __restrict__ bta,
        const float* __restrict__ mu, const float* __restrict__ va,
        float* __restrict__ h1, const float* __restrict__ zrow) {
    const int blk = xcd_swz(blockIdx.x, 2500);
    const int co = threadIdx.x & 31, vs = threadIdx.x >> 5;
    const int li = blk * 16 + vs * 2;
    const int p0 = list[li], p1 = list[li + 1];
    const int z0 = (p0 >> 12) & 15, y0 = (p0 >> 6) & 63, x0 = p0 & 63;
    const int z1 = (p1 >> 12) & 15, y1 = (p1 >> 6) & 63, x1 = p1 & 63;
    float acc0 = 0.f, acc1 = 0.f;
    #pragma unroll 3
    for (int t = 0; t < 27; ++t) {
        const int dz = t / 9 - 1, dy = (t / 3) % 3 - 1, dx = t % 3 - 1;
        const int off = dz * 4096 + dy * 64 + dx;
        bool ok0 = (unsigned)(z0 + dz) < Dd && (unsigned)(y0 + dy) < Hh && (unsigned)(x0 + dx) < Ww;
        bool ok1 = (unsigned)(z1 + dz) < Dd && (unsigned)(y1 + dy) < Hh && (unsigned)(x1 + dx) < Ww;
        const float* i0 = ok0 ? dense16 + (size_t)(p0 + off) * 16 : zrow;
        const float* i1 = ok1 ? dense16 + (size_t)(p1 + off) * 16 : zrow;
        const float* wt = w1 + t * 512 + co;
        #pragma unroll
        for (int c4 = 0; c4 < 4; ++c4) {
            float4 a0 = *(const float4*)(i0 + c4 * 4);
            float4 a1 = *(const float4*)(i1 + c4 * 4);
            float w0 = wt[(c4 * 4 + 0) * 32], w1v = wt[(c4 * 4 + 1) * 32];
            float w2v = wt[(c4 * 4 + 2) * 32], w3v = wt[(c4 * 4 + 3) * 32];
            acc0 = fmaf(a0.x, w0, acc0);  acc1 = fmaf(a1.x, w0, acc1);
            acc0 = fmaf(a0.y, w1v, acc0); acc1 = fmaf(a1.y, w1v, acc1);
            acc0 = fmaf(a0.z, w2v, acc0); acc1 = fmaf(a1.z, w2v, acc1);
            acc0 = fmaf(a0.w, w3v, acc0); acc1 = fmaf(a1.w, w3v, acc1);
        }
    }
    const float s = g[co] * (1.0f / sqrtf(va[co] + EPSf));
    const float sh = bta[co], m = mu[co];
    h1[(size_t)p0 * 32 + co] = fmaxf(0.f, fmaf(acc0 - m, s, sh));
    h1[(size_t)p1 * 32 + co] = fmaxf(0.f, fmaf(acc1 - m, s, sh));
}

// ---------------- conv2 32->64 + BN + ReLU ----------------
__global__ void __launch_bounds__(256, 4) k_conv2(const int* __restrict__ list,
        const float* __restrict__ h1, const float* __restrict__ w2,
        const float* __restrict__ g, const float* __restrict__ bta,
        const float* __restrict__ mu, const float* __restrict__ va,
        float* __restrict__ h2, const float* __restrict__ zrow) {
    const int blk = xcd_swz(blockIdx.x, 5000);
    const int co = threadIdx.x & 63, vs = threadIdx.x >> 6;
    const int li = blk * 8 + vs * 2;
    const int p0 = list[li], p1 = list[li + 1];
    const int z0 = (p0 >> 12) & 15, y0 = (p0 >> 6) & 63, x0 = p0 & 63;
    const int z1 = (p1 >> 12) & 15, y1 = (p1 >> 6) & 63, x1 = p1 & 63;
    float acc0 = 0.f, acc1 = 0.f;
    #pragma unroll 3
    for (int t = 0; t < 27; ++t) {
        const int dz = t / 9 - 1, dy = (t / 3) % 3 - 1, dx = t % 3 - 1;
        const int off = dz * 4096 + dy * 64 + dx;
        bool ok0 = (unsigned)(z0 + dz) < Dd && (unsigned)(y0 + dy) < Hh && (unsigned)(x0 + dx) < Ww;
        bool ok1 = (unsigned)(z1 + dz) < Dd && (unsigned)(y1 + dy) < Hh && (unsigned)(x1 + dx) < Ww;
        const float* i0 = ok0 ? h1 + (size_t)(p0 + off) * 32 : zrow;
        const float* i1 = ok1 ? h1 + (size_t)(p1 + off) * 32 : zrow;
        const float* wt = w2 + t * 2048 + co;
        #pragma unroll
        for (int c4 = 0; c4 < 8; ++c4) {
            float4 a0 = *(const float4*)(i0 + c4 * 4);
            float4 a1 = *(const float4*)(i1 + c4 * 4);
            float w0 = wt[(c4 * 4 + 0) * 64], w1v = wt[(c4 * 4 + 1) * 64];
            float w2v = wt[(c4 * 4 + 2) * 64], w3v = wt[(c4 * 4 + 3) * 64];
            acc0 = fmaf(a0.x, w0, acc0);  acc1 = fmaf(a1.x, w0, acc1);
            acc0 = fmaf(a0.y, w1v, acc0); acc1 = fmaf(a1.y, w1v, acc1);
            acc0 = fmaf(a0.z, w2v, acc0); acc1 = fmaf(a1.z, w2v, acc1);
            acc0 = fmaf(a0.w, w3v, acc0); acc1 = fmaf(a1.w, w3v, acc1);
        }
    }
    const float s = g[co] * (1.0f / sqrtf(va[co] + EPSf));
    const float sh = bta[co], m = mu[co];
    h2[(size_t)p0 * 64 + co] = fmaxf(0.f, fmaf(acc0 - m, s, sh));
    h2[(size_t)p1 * 64 + co] = fmaxf(0.f, fmaf(acc1 - m, s, sh));
}

// ---------------- importance conv 64->27 ----------------
__global__ void __launch_bounds__(256, 4) k_imp(const int* __restrict__ list,
        const float* __restrict__ h2, const float* __restrict__ wimp,
        uint32_t* __restrict__ u_logits, uint32_t* __restrict__ kbits,
        const float* __restrict__ zrow) {
    const int blk = xcd_swz(blockIdx.x, 2500);
    const int lane = threadIdx.x & 63;
    const int co = threadIdx.x & 31, vs = threadIdx.x >> 5;
    const int coe = co < 27 ? co : 0;
    const int li = blk * 16 + vs * 2;
    const int p0 = list[li], p1 = list[li + 1];
    const int z0 = (p0 >> 12) & 15, y0 = (p0 >> 6) & 63, x0 = p0 & 63;
    const int z1 = (p1 >> 12) & 15, y1 = (p1 >> 6) & 63, x1 = p1 & 63;
    float acc0 = 0.f, acc1 = 0.f;
    #pragma unroll 3
    for (int t = 0; t < 27; ++t) {
        const int dz = t / 9 - 1, dy = (t / 3) % 3 - 1, dx = t % 3 - 1;
        const int off = dz * 4096 + dy * 64 + dx;
        bool ok0 = (unsigned)(z0 + dz) < Dd && (unsigned)(y0 + dy) < Hh && (unsigned)(x0 + dx) < Ww;
        bool ok1 = (unsigned)(z1 + dz) < Dd && (unsigned)(y1 + dy) < Hh && (unsigned)(x1 + dx) < Ww;
        const float* i0 = ok0 ? h2 + (size_t)(p0 + off) * 64 : zrow;
        const float* i1 = ok1 ? h2 + (size_t)(p1 + off) * 64 : zrow;
        const float* wt = wimp + t * 1728 + coe;
        #pragma unroll
        for (int c4 = 0; c4 < 16; ++c4) {
            float4 a0 = *(const float4*)(i0 + c4 * 4);
            float4 a1 = *(const float4*)(i1 + c4 * 4);
            float w0 = wt[(c4 * 4 + 0) * 27], w1v = wt[(c4 * 4 + 1) * 27];
            float w2v = wt[(c4 * 4 + 2) * 27], w3v = wt[(c4 * 4 + 3) * 27];
            acc0 = fmaf(a0.x, w0, acc0);  acc1 = fmaf(a1.x, w0, acc1);
            acc0 = fmaf(a0.y, w1v, acc0); acc1 = fmaf(a1.y, w1v, acc1);
            acc0 = fmaf(a0.z, w2v, acc0); acc1 = fmaf(a1.z, w2v, acc1);
            acc0 = fmaf(a0.w, w3v, acc0); acc1 = fmaf(a1.w, w3v, acc1);
        }
    }
    unsigned long long mb0 = __ballot(co < 26 && acc0 >= 0.0f);
    unsigned long long mb1 = __ballot(co < 26 && acc1 >= 0.0f);
    if ((lane & 31) == 0) {
        kbits[li]     = (uint32_t)(mb0 >> (lane & 32)) & 0x3FFFFFFu;
        kbits[li + 1] = (uint32_t)(mb1 >> (lane & 32)) & 0x3FFFFFFu;
    }
    if (co == 26) {
        u_logits[li]     = f2sort(acc0);
        u_logits[li + 1] = f2sort(acc1);
    }
}

// ---------------- exact kth-largest ----------------
__global__ void __launch_bounds__(256) k_select(const uint32_t* __restrict__ u_all,
                                                uint32_t* __restrict__ kth_u) {
    const int b = blockIdx.x;
    const uint32_t* u = u_all + (size_t)b * NVb;
    __shared__ int hist[256];
    __shared__ int s_d, s_above;
    uint32_t prefix = 0;
    int K = KFORE;
    for (int p = 3; p >= 0; --p) {
        hist[threadIdx.x] = 0;
        __syncthreads();
        const int sh = p * 8;
        for (int i = threadIdx.x; i < NVb; i += 256) {
            uint32_t ui = u[i];
            bool cand;
            if (p == 3) cand = true;
            else cand = ((ui >> (sh + 8)) == prefix);
            if (cand) atomicAdd(&hist[(ui >> sh) & 255], 1);
        }
        __syncthreads();
        if (threadIdx.x == 0) {
            int cum = 0, d = 255;
            for (; d >= 0; --d) { cum += hist[d]; if (cum >= K) break; }
            s_d = d; s_above = cum - hist[d];
        }
        __syncthreads();
        prefix = (prefix << 8) | (uint32_t)s_d;
        K -= s_above;
        __syncthreads();
    }
    if (threadIdx.x == 0) kth_u[b] = prefix;
}

// ---------------- dilation ----------------
__global__ void __launch_bounds__(256) k_dilate(const int* __restrict__ list,
                                                const uint32_t* __restrict__ u_logits,
                                                const uint32_t* __restrict__ kbits,
                                                const uint32_t* __restrict__ kth_u,
                                                uint8_t* __restrict__ new_act) {
    int i = blockIdx.x * 256 + threadIdx.x;
    if (i >= NACT) return;
    int pos = list[i];
    int b = pos >> 16;
    if (u_logits[i] < kth_u[b]) return;
    int z = (pos >> 12) & 15, y = (pos >> 6) & 63, x = pos & 63;
    uint32_t bits = kbits[i];
    while (bits) {
        int ch = __ffs(bits) - 1;
        bits &= bits - 1;
        int l = ch + (ch >= 13 ? 1 : 0);
        int oz = l / 9 - 1, oy = (l / 3) % 3 - 1, ox = l % 3 - 1;
        int tz = z + oz, ty = y + oy, tx = x + ox;
        if (tz >= 1 && tz < Dd && ty >= 1 && ty < Hh && tx >= 1 && tx < Ww)
            new_act[((b * Dd + tz) * Hh + ty) * Ww + tx] = 1;
    }
}

// ---------------- h2 f32 -> bf16 (dense) ----------------
__global__ void __launch_bounds__(256) k_cvt(const float* __restrict__ h2,
                                             unsigned short* __restrict__ h2b) {
    int i = (blockIdx.x * 256 + threadIdx.x) * 4;
    float4 f = *(const float4*)(h2 + i);
    us4 o = { f2b(f.x), f2b(f.y), f2b(f.z), f2b(f.w) };
    *(us4*)(h2b + i) = o;
}

// ---------------- w_focal f32 [27][64][128] -> bf16 transposed [27][128][64] ----------------
__global__ void __launch_bounds__(256) k_wcvt(const float* __restrict__ wf,
                                              unsigned short* __restrict__ wfb) {
    int i = blockIdx.x * 256 + threadIdx.x;   // 221184 total
    int t = i >> 13, r = i & 8191, n = r >> 6, k = r & 63;
    wfb[i] = f2b(wf[(t * 64 + k) * 128 + n]);
}

// ---------------- focal conv 64->128 via bf16 MFMA ----------------
// block: 256 thr (4 waves), 64 voxels, N=128 (32 ch/wave). A staged per-tap in LDS.
__global__ void __launch_bounds__(256, 4) k_focal(
        const int* __restrict__ list, const int* __restrict__ count,
        const unsigned short* __restrict__ h2b, const unsigned short* __restrict__ wfb,
        const float* __restrict__ g, const float* __restrict__ bta,
        const float* __restrict__ mu, const float* __restrict__ va,
        float* __restrict__ out, const unsigned short* __restrict__ zb) {
    __shared__ __align__(16) unsigned short As[2][64 * 72];  // +8 pad: conflict-free b128
    __shared__ int s_pos[64];
    const int n = *count;
    const int i0 = xcd_swz(blockIdx.x, 2048) * 64;
    if (i0 >= n) return;
    const int tid = threadIdx.x;
    const int wv = tid >> 6, lane = tid & 63;
    if (tid < 64) { int idx = i0 + tid; s_pos[tid] = idx < n ? list[idx] : -1; }
    __syncthreads();
    const int v0 = tid >> 3, c8 = tid & 7, v1 = v0 + 32;
    const int p0 = s_pos[v0], p1 = s_pos[v1];
    const int z0 = (p0 >> 12) & 15, y0 = (p0 >> 6) & 63, x0 = p0 & 63;
    const int z1 = (p1 >> 12) & 15, y1 = (p1 >> 6) & 63, x1 = p1 & 63;
    const int hi = lane >> 4, lo = lane & 15;
    const int cb = wv * 32;

    f32x4 acc[4][2];
    #pragma unroll
    for (int mi = 0; mi < 4; ++mi)
        #pragma unroll
        for (int ni = 0; ni < 2; ++ni) acc[mi][ni] = (f32x4){0.f, 0.f, 0.f, 0.f};

    auto stage_src = [&](int t, const unsigned short*& a0, const unsigned short*& a1) {
        int dz = t / 9 - 1, dy = (t / 3) % 3 - 1, dx = t % 3 - 1;
        int off = dz * 4096 + dy * 64 + dx;
        bool ok0 = p0 >= 0 && (unsigned)(z0 + dz) < Dd && (unsigned)(y0 + dy) < Hh && (unsigned)(x0 + dx) < Ww;
        bool ok1 = p1 >= 0 && (unsigned)(z1 + dz) < Dd && (unsigned)(y1 + dy) < Hh && (unsigned)(x1 + dx) < Ww;
        a0 = ok0 ? h2b + (size_t)(p0 + off) * 64 + c8 * 8 : zb;
        a1 = ok1 ? h2b + (size_t)(p1 + off) * 64 + c8 * 8 : zb;
    };

    // prologue: stage tap 0
    {
        const unsigned short *a0p, *a1p;
        stage_src(0, a0p, a1p);
        short8 r0 = *(const short8*)a0p, r1 = *(const short8*)a1p;
        *(short8*)&As[0][v0 * 72 + c8 * 8] = r0;
        *(short8*)&As[0][v1 * 72 + c8 * 8] = r1;
    }
    __syncthreads();

    for (int t = 0; t < 27; ++t) {
        const int cur = t & 1;
        short8 r0, r1;
        if (t < 26) {   // prefetch next tap into regs while computing
            const unsigned short *a0p, *a1p;
            stage_src(t + 1, a0p, a1p);
            r0 = *(const short8*)a0p;
            r1 = *(const short8*)a1p;
        }
        short8 bfr[4];
        #pragma unroll
        for (int ni = 0; ni < 2; ++ni)
            #pragma unroll
            for (int ks = 0; ks < 2; ++ks)
                bfr[ni * 2 + ks] = *(const short8*)(wfb + (size_t)t * 8192
                                    + (size_t)(cb + ni * 16 + lo) * 64 + ks * 32 + hi * 8);
        #pragma unroll
        for (int ks = 0; ks < 2; ++ks) {
            short8 a[4];
            #pragma unroll
            for (int mi = 0; mi < 4; ++mi)
                a[mi] = *(const short8*)&As[cur][(mi * 16 + lo) * 72 + ks * 32 + hi * 8];
            #pragma unroll
            for (int mi = 0; mi < 4; ++mi)
                #pragma unroll
                for (int ni = 0; ni < 2; ++ni)
                    acc[mi][ni] = __builtin_amdgcn_mfma_f32_16x16x32_bf16(
                        a[mi], bfr[ni * 2 + ks], acc[mi][ni], 0, 0, 0);
        }
        if (t < 26) {
            *(short8*)&As[1 - cur][v0 * 72 + c8 * 8] = r0;
            *(short8*)&As[1 - cur][v1 * 72 + c8 * 8] = r1;
            __syncthreads();
        }
    }

    #pragma unroll
    for (int ni = 0; ni < 2; ++ni) {
        const int ch = cb + ni * 16 + lo;
        const float s = g[ch] * (1.0f / sqrtf(va[ch] + EPSf));
        const float sh = bta[ch], mm = mu[ch];
        #pragma unroll
        for (int mi = 0; mi < 4; ++mi)
            #pragma unroll
            for (int j = 0; j < 4; ++j) {
                int vi = mi * 16 + hi * 4 + j;
                if (i0 + vi < n)
                    out[(size_t)s_pos[vi] * 128 + ch] = fmaxf(0.f, fmaf(acc[mi][ni][j] - mm, s, sh));
            }
    }
}

extern "C" void kernel_launch(void* const* d_in, const int* in_sizes, int n_in,
                              void* d_out, int out_size, void* d_ws, size_t ws_size,
                              hipStream_t stream) {
    (void)in_sizes; (void)n_in; (void)ws_size;
    const float* feat   = (const float*)d_in[0];
    const int*   coords = (const int*)d_in[1];
    const float* w1   = (const float*)d_in[2];
    const float* w2   = (const float*)d_in[3];
    const float* wimp = (const float*)d_in[4];
    const float* wf   = (const float*)d_in[5];
    const float* g1 = (const float*)d_in[6],  *b1 = (const float*)d_in[7];
    const float* m1 = (const float*)d_in[8],  *v1 = (const float*)d_in[9];
    const float* g2 = (const float*)d_in[10], *b2 = (const float*)d_in[11];
    const float* m2 = (const float*)d_in[12], *v2 = (const float*)d_in[13];
    const float* g3 = (const float*)d_in[14], *b3 = (const float*)d_in[15];
    const float* m3 = (const float*)d_in[16], *v3 = (const float*)d_in[17];

    char* ws = (char*)d_ws;
    float*    dense16  = (float*)(ws + 0);           //  8,388,608 B (wfb overlays after conv1)
    float*    h1       = (float*)(ws + 8388608);     // 16,777,216 B (h2b overlays after conv2)
    float*    h2       = (float*)(ws + 25165824);    // 33,554,432 B
    uint8_t*  active   = (uint8_t*)(ws + 58720256);  //    131,072 B
    uint8_t*  new_act  = (uint8_t*)(ws + 58851328);  //    131,072 B
    float*    zrow     = (float*)(ws + 58982400);    //        256 B zeros
    int*      count    = (int*)(ws + 58982656);      //        256 B
    const size_t MEMSET_BYTES = 58982912;
    uint32_t* u_logits = (uint32_t*)(ws + 58982912); //    160,000 B
    uint32_t* kbits    = (uint32_t*)(ws + 59142912); //    160,000 B
    uint32_t* kth_u    = (uint32_t*)(ws + 59302912); //        256 B
    int*      list     = (int*)(ws + 59303168);      //    524,288 B (act list, then focal list)

    unsigned short* wfb = (unsigned short*)dense16;  // [27][128][64] bf16, after conv1
    unsigned short* h2b = (unsigned short*)h1;       // [131072][64] bf16, after conv2

    hipMemsetAsync(d_ws, 0, MEMSET_BYTES, stream);
    hipMemsetAsync(d_out, 0, (size_t)out_size * sizeof(float), stream);

    k_scatter<<<157, 256, 0, stream>>>(feat, coords, dense16, active, new_act);
    k_compact<<<1, 1024, 0, stream>>>(active, list, count);          // ordered active list
    k_conv1<<<2500, 256, 0, stream>>>(list, dense16, w1, g1, b1, m1, v1, h1, zrow);
    k_wcvt<<<864, 256, 0, stream>>>(wf, wfb);                        // dense16 now dead
    k_conv2<<<5000, 256, 0, stream>>>(list, h1, w2, g2, b2, m2, v2, h2, zrow);
    k_cvt<<<8192, 256, 0, stream>>>(h2, h2b);                        // h1 now dead
    k_imp<<<2500, 256, 0, stream>>>(list, h2, wimp, u_logits, kbits, zrow);
    k_select<<<2, 256, 0, stream>>>(u_logits, kth_u);
    k_dilate<<<157, 256, 0, stream>>>(list, u_logits, kbits, kth_u, new_act);
    k_compact<<<1, 1024, 0, stream>>>(new_act, list, count);         // focal list
    k_focal<<<2048, 256, 0, stream>>>(list, count, h2b, wfb, g3, b3, m3, v3,
                                      (float*)d_out, (const unsigned short*)zrow);
}

// Round 4
// 897.245 us; speedup vs baseline: 4.4953x; 1.7281x over previous
//
#include <hip/hip_runtime.h>
#include <stdint.h>

#define Dd 16
#define Hh 64
#define Ww 64
#define NACT 40000
#define NVb 20000
#define KFORE 10000
#define EPSf 0.001f

typedef __attribute__((ext_vector_type(8))) short short8;   // 8 bf16 (4 VGPR)
typedef __attribute__((ext_vector_type(4))) float f32x4;
typedef __attribute__((ext_vector_type(4))) unsigned short us4;

static __device__ __forceinline__ uint32_t f2sort(float f) {
    uint32_t u = __float_as_uint(f);
    return (u & 0x80000000u) ? ~u : (u | 0x80000000u);
}

// round-to-nearest-even f32 -> bf16 bits (inputs finite)
static __device__ __forceinline__ unsigned short f2b(float f) {
    uint32_t u = __float_as_uint(f);
    return (unsigned short)((u + 0x7FFFu + ((u >> 16) & 1u)) >> 16);
}

// bijective XCD-contiguous remap (m204)
static __device__ __forceinline__ int xcd_swz(int orig, int nwg) {
    int xcd = orig & 7, idx = orig >> 3;
    int q = nwg >> 3, r = nwg & 7;
    int base = xcd < r ? xcd * (q + 1) : r * (q + 1) + (xcd - r) * q;
    return base + idx;
}

// ---------------- scatter features to dense grid ----------------
__global__ void __launch_bounds__(256) k_scatter(const float* __restrict__ feat,
                                                 const int* __restrict__ coords,
                                                 float* __restrict__ dense16,
                                                 uint8_t* __restrict__ active,
                                                 uint8_t* __restrict__ new_act) {
    int i = blockIdx.x * 256 + threadIdx.x;
    if (i >= NACT) return;
    int b = coords[i * 4 + 0], z = coords[i * 4 + 1], y = coords[i * 4 + 2], x = coords[i * 4 + 3];
    int pos = ((b * Dd + z) * Hh + y) * Ww + x;
    active[pos] = 1;
    new_act[pos] = 1;
    const float4* f4 = (const float4*)(feat + (size_t)i * 16);
    float4* d4 = (float4*)(dense16 + (size_t)pos * 16);
    d4[0] = f4[0]; d4[1] = f4[1]; d4[2] = f4[2]; d4[3] = f4[3];
}

// ---------------- ordered compaction (position-sorted list) ----------------
__global__ void __launch_bounds__(1024) k_compact(const uint8_t* __restrict__ mask,
                                                  int* __restrict__ list, int* __restrict__ count) {
    __shared__ int s[1024];
    const int tid = threadIdx.x;
    const int base = tid * 128;
    int c = 0;
    for (int j = 0; j < 128; ++j) c += mask[base + j];
    s[tid] = c;
    __syncthreads();
    for (int off = 1; off < 1024; off <<= 1) {
        int v = s[tid];
        if (tid >= off) v += s[tid - off];
        __syncthreads();
        s[tid] = v;
        __syncthreads();
    }
    if (tid == 1023) *count = s[1023];
    int idx = s[tid] - c;
    for (int j = 0; j < 128; ++j)
        if (mask[base + j]) list[idx++] = base + j;
}

// ---------------- conv1 16->32 + BN + ReLU : thread-per-voxel, 16 ch/part ----------------
__global__ void __launch_bounds__(256) k_conv1(const int* __restrict__ list,
        const float* __restrict__ dense16, const float* __restrict__ w1,
        const float* __restrict__ g, const float* __restrict__ bta,
        const float* __restrict__ mu, const float* __restrict__ va,
        float* __restrict__ h1) {
    const int i = xcd_swz(blockIdx.x, 157) * 256 + threadIdx.x;
    if (i >= NACT) return;
    const int cb = blockIdx.y * 16;          // uniform -> scalar weight loads
    const int pos = list[i];
    const int z = (pos >> 12) & 15, y = (pos >> 6) & 63, x = pos & 63;
    float acc[16];
    #pragma unroll
    for (int c = 0; c < 16; ++c) acc[c] = 0.f;
    for (int t = 0; t < 27; ++t) {
        const int dz = t / 9 - 1, dy = (t / 3) % 3 - 1, dx = t % 3 - 1;
        if (!((unsigned)(z + dz) < Dd && (unsigned)(y + dy) < Hh && (unsigned)(x + dx) < Ww)) continue;
        const float* row = dense16 + (size_t)(pos + dz * 4096 + dy * 64 + dx) * 16;
        const float* wt = w1 + t * 512 + cb;
        #pragma unroll
        for (int k4 = 0; k4 < 4; ++k4) {
            float4 xv = *(const float4*)(row + k4 * 4);
            float xs[4] = {xv.x, xv.y, xv.z, xv.w};
            #pragma unroll
            for (int j = 0; j < 4; ++j)
                #pragma unroll
                for (int c = 0; c < 16; ++c)
                    acc[c] = fmaf(xs[j], wt[(k4 * 4 + j) * 32 + c], acc[c]);
        }
    }
    #pragma unroll
    for (int c4 = 0; c4 < 4; ++c4) {
        float4 o;
        float* op = (float*)&o;
        #pragma unroll
        for (int j = 0; j < 4; ++j) {
            const int c = cb + c4 * 4 + j;
            const float s = g[c] * (1.0f / sqrtf(va[c] + EPSf));
            op[j] = fmaxf(0.f, fmaf(acc[c4 * 4 + j] - mu[c], s, bta[c]));
        }
        *(float4*)(h1 + (size_t)pos * 32 + cb + c4 * 4) = o;
    }
}

// ---------------- conv2 32->64 + BN + ReLU : thread-per-voxel, 16 ch/part ----------------
__global__ void __launch_bounds__(256) k_conv2(const int* __restrict__ list,
        const float* __restrict__ h1, const float* __restrict__ w2,
        const float* __restrict__ g, const float* __restrict__ bta,
        const float* __restrict__ mu, const float* __restrict__ va,
        float* __restrict__ h2) {
    const int i = xcd_swz(blockIdx.x, 157) * 256 + threadIdx.x;
    if (i >= NACT) return;
    const int cb = blockIdx.y * 16;          // 4 parts
    const int pos = list[i];
    const int z = (pos >> 12) & 15, y = (pos >> 6) & 63, x = pos & 63;
    float acc[16];
    #pragma unroll
    for (int c = 0; c < 16; ++c) acc[c] = 0.f;
    for (int t = 0; t < 27; ++t) {
        const int dz = t / 9 - 1, dy = (t / 3) % 3 - 1, dx = t % 3 - 1;
        if (!((unsigned)(z + dz) < Dd && (unsigned)(y + dy) < Hh && (unsigned)(x + dx) < Ww)) continue;
        const float* row = h1 + (size_t)(pos + dz * 4096 + dy * 64 + dx) * 32;
        const float* wt = w2 + t * 2048 + cb;
        #pragma unroll
        for (int k4 = 0; k4 < 8; ++k4) {
            float4 xv = *(const float4*)(row + k4 * 4);
            float xs[4] = {xv.x, xv.y, xv.z, xv.w};
            #pragma unroll
            for (int j = 0; j < 4; ++j)
                #pragma unroll
                for (int c = 0; c < 16; ++c)
                    acc[c] = fmaf(xs[j], wt[(k4 * 4 + j) * 64 + c], acc[c]);
        }
    }
    #pragma unroll
    for (int c4 = 0; c4 < 4; ++c4) {
        float4 o;
        float* op = (float*)&o;
        #pragma unroll
        for (int j = 0; j < 4; ++j) {
            const int c = cb + c4 * 4 + j;
            const float s = g[c] * (1.0f / sqrtf(va[c] + EPSf));
            op[j] = fmaxf(0.f, fmaf(acc[c4 * 4 + j] - mu[c], s, bta[c]));
        }
        *(float4*)(h2 + (size_t)pos * 64 + cb + c4 * 4) = o;
    }
}

// ---------------- importance conv 64->27 : thread-per-voxel, 2 ch-parts ----------------
template<int CB, int NC>
static __device__ __forceinline__ void imp_body(int i, int pos,
        const float* __restrict__ h2, const float* __restrict__ wimp,
        uint32_t* __restrict__ u_logits, uint32_t* __restrict__ kb) {
    const int z = (pos >> 12) & 15, y = (pos >> 6) & 63, x = pos & 63;
    float acc[NC];
    #pragma unroll
    for (int c = 0; c < NC; ++c) acc[c] = 0.f;
    for (int t = 0; t < 27; ++t) {
        const int dz = t / 9 - 1, dy = (t / 3) % 3 - 1, dx = t % 3 - 1;
        if (!((unsigned)(z + dz) < Dd && (unsigned)(y + dy) < Hh && (unsigned)(x + dx) < Ww)) continue;
        const float* row = h2 + (size_t)(pos + dz * 4096 + dy * 64 + dx) * 64;
        const float* wt = wimp + t * 1728 + CB;
        #pragma unroll
        for (int k4 = 0; k4 < 16; ++k4) {
            float4 xv = *(const float4*)(row + k4 * 4);
            float xs[4] = {xv.x, xv.y, xv.z, xv.w};
            #pragma unroll
            for (int j = 0; j < 4; ++j)
                #pragma unroll
                for (int c = 0; c < NC; ++c)
                    acc[c] = fmaf(xs[j], wt[(k4 * 4 + j) * 27 + c], acc[c]);
        }
    }
    if (CB == 0) {
        uint32_t bits = 0;
        #pragma unroll
        for (int c = 0; c < 14; ++c) bits |= (acc[c] >= 0.f ? 1u : 0u) << c;
        kb[i] = bits;
    } else {
        uint32_t bits = 0;
        #pragma unroll
        for (int c = 0; c < 12; ++c) bits |= (acc[c] >= 0.f ? 1u : 0u) << c;  // ch 14..25
        kb[i] = bits;
        u_logits[i] = f2sort(acc[12]);   // ch 26
    }
}

__global__ void __launch_bounds__(256) k_imp(const int* __restrict__ list,
        const float* __restrict__ h2, const float* __restrict__ wimp,
        uint32_t* __restrict__ u_logits,
        uint32_t* __restrict__ kb_lo, uint32_t* __restrict__ kb_hi) {
    const int i = xcd_swz(blockIdx.x, 157) * 256 + threadIdx.x;
    if (i >= NACT) return;
    const int pos = list[i];
    if (blockIdx.y == 0) imp_body<0, 14>(i, pos, h2, wimp, u_logits, kb_lo);
    else                 imp_body<14, 13>(i, pos, h2, wimp, u_logits, kb_hi);
}

// ---------------- exact kth-largest ----------------
__global__ void __launch_bounds__(256) k_select(const uint32_t* __restrict__ u_all,
                                                uint32_t* __restrict__ kth_u) {
    const int b = blockIdx.x;
    const uint32_t* u = u_all + (size_t)b * NVb;
    __shared__ int hist[256];
    __shared__ int s_d, s_above;
    uint32_t prefix = 0;
    int K = KFORE;
    for (int p = 3; p >= 0; --p) {
        hist[threadIdx.x] = 0;
        __syncthreads();
        const int sh = p * 8;
        for (int i = threadIdx.x; i < NVb; i += 256) {
            uint32_t ui = u[i];
            bool cand;
            if (p == 3) cand = true;
            else cand = ((ui >> (sh + 8)) == prefix);
            if (cand) atomicAdd(&hist[(ui >> sh) & 255], 1);
        }
        __syncthreads();
        if (threadIdx.x == 0) {
            int cum = 0, d = 255;
            for (; d >= 0; --d) { cum += hist[d]; if (cum >= K) break; }
            s_d = d; s_above = cum - hist[d];
        }
        __syncthreads();
        prefix = (prefix << 8) | (uint32_t)s_d;
        K -= s_above;
        __syncthreads();
    }
    if (threadIdx.x == 0) kth_u[b] = prefix;
}

// ---------------- dilation ----------------
__global__ void __launch_bounds__(256) k_dilate(const int* __restrict__ list,
                                                const uint32_t* __restrict__ u_logits,
                                                const uint32_t* __restrict__ kb_lo,
                                                const uint32_t* __restrict__ kb_hi,
                                                const uint32_t* __restrict__ kth_u,
                                                uint8_t* __restrict__ new_act) {
    int i = blockIdx.x * 256 + threadIdx.x;
    if (i >= NACT) return;
    int pos = list[i];
    int b = pos >> 16;
    if (u_logits[i] < kth_u[b]) return;
    int z = (pos >> 12) & 15, y = (pos >> 6) & 63, x = pos & 63;
    uint32_t bits = kb_lo[i] | (kb_hi[i] << 14);
    while (bits) {
        int ch = __ffs(bits) - 1;
        bits &= bits - 1;
        int l = ch + (ch >= 13 ? 1 : 0);
        int oz = l / 9 - 1, oy = (l / 3) % 3 - 1, ox = l % 3 - 1;
        int tz = z + oz, ty = y + oy, tx = x + ox;
        if (tz >= 1 && tz < Dd && ty >= 1 && ty < Hh && tx >= 1 && tx < Ww)
            new_act[((b * Dd + tz) * Hh + ty) * Ww + tx] = 1;
    }
}

// ---------------- h2 f32 -> bf16 (dense) ----------------
__global__ void __launch_bounds__(256) k_cvt(const float* __restrict__ h2,
                                             unsigned short* __restrict__ h2b) {
    int i = (blockIdx.x * 256 + threadIdx.x) * 4;
    float4 f = *(const float4*)(h2 + i);
    us4 o = { f2b(f.x), f2b(f.y), f2b(f.z), f2b(f.w) };
    *(us4*)(h2b + i) = o;
}

// ---------------- w_focal f32 [27][64][128] -> bf16 transposed [27][128][64] ----------------
__global__ void __launch_bounds__(256) k_wcvt(const float* __restrict__ wf,
                                              unsigned short* __restrict__ wfb) {
    int i = blockIdx.x * 256 + threadIdx.x;   // 221184 total
    int t = i >> 13, r = i & 8191, n = r >> 6, k = r & 63;
    wfb[i] = f2b(wf[(t * 64 + k) * 128 + n]);
}

// ---------------- focal conv 64->128 via bf16 MFMA ----------------
__global__ void __launch_bounds__(256, 4) k_focal(
        const int* __restrict__ list, const int* __restrict__ count,
        const unsigned short* __restrict__ h2b, const unsigned short* __restrict__ wfb,
        const float* __restrict__ g, const float* __restrict__ bta,
        const float* __restrict__ mu, const float* __restrict__ va,
        float* __restrict__ out, const unsigned short* __restrict__ zb) {
    __shared__ __align__(16) unsigned short As[2][64 * 72];  // +8 pad: conflict-free b128
    __shared__ int s_pos[64];
    const int n = *count;
    const int i0 = xcd_swz(blockIdx.x, 2048) * 64;
    if (i0 >= n) return;
    const int tid = threadIdx.x;
    const int wv = tid >> 6, lane = tid & 63;
    if (tid < 64) { int idx = i0 + tid; s_pos[tid] = idx < n ? list[idx] : -1; }
    __syncthreads();
    const int v0 = tid >> 3, c8 = tid & 7, v1 = v0 + 32;
    const int p0 = s_pos[v0], p1 = s_pos[v1];
    const int z0 = (p0 >> 12) & 15, y0 = (p0 >> 6) & 63, x0 = p0 & 63;
    const int z1 = (p1 >> 12) & 15, y1 = (p1 >> 6) & 63, x1 = p1 & 63;
    const int hi = lane >> 4, lo = lane & 15;
    const int cb = wv * 32;

    f32x4 acc[4][2];
    #pragma unroll
    for (int mi = 0; mi < 4; ++mi)
        #pragma unroll
        for (int ni = 0; ni < 2; ++ni) acc[mi][ni] = (f32x4){0.f, 0.f, 0.f, 0.f};

    auto stage_src = [&](int t, const unsigned short*& a0, const unsigned short*& a1) {
        int dz = t / 9 - 1, dy = (t / 3) % 3 - 1, dx = t % 3 - 1;
        int off = dz * 4096 + dy * 64 + dx;
        bool ok0 = p0 >= 0 && (unsigned)(z0 + dz) < Dd && (unsigned)(y0 + dy) < Hh && (unsigned)(x0 + dx) < Ww;
        bool ok1 = p1 >= 0 && (unsigned)(z1 + dz) < Dd && (unsigned)(y1 + dy) < Hh && (unsigned)(x1 + dx) < Ww;
        a0 = ok0 ? h2b + (size_t)(p0 + off) * 64 + c8 * 8 : zb;
        a1 = ok1 ? h2b + (size_t)(p1 + off) * 64 + c8 * 8 : zb;
    };

    {
        const unsigned short *a0p, *a1p;
        stage_src(0, a0p, a1p);
        short8 r0 = *(const short8*)a0p, r1 = *(const short8*)a1p;
        *(short8*)&As[0][v0 * 72 + c8 * 8] = r0;
        *(short8*)&As[0][v1 * 72 + c8 * 8] = r1;
    }
    __syncthreads();

    for (int t = 0; t < 27; ++t) {
        const int cur = t & 1;
        short8 r0, r1;
        if (t < 26) {
            const unsigned short *a0p, *a1p;
            stage_src(t + 1, a0p, a1p);
            r0 = *(const short8*)a0p;
            r1 = *(const short8*)a1p;
        }
        short8 bfr[4];
        #pragma unroll
        for (int ni = 0; ni < 2; ++ni)
            #pragma unroll
            for (int ks = 0; ks < 2; ++ks)
                bfr[ni * 2 + ks] = *(const short8*)(wfb + (size_t)t * 8192
                                    + (size_t)(cb + ni * 16 + lo) * 64 + ks * 32 + hi * 8);
        #pragma unroll
        for (int ks = 0; ks < 2; ++ks) {
            short8 a[4];
            #pragma unroll
            for (int mi = 0; mi < 4; ++mi)
                a[mi] = *(const short8*)&As[cur][(mi * 16 + lo) * 72 + ks * 32 + hi * 8];
            #pragma unroll
            for (int mi = 0; mi < 4; ++mi)
                #pragma unroll
                for (int ni = 0; ni < 2; ++ni)
                    acc[mi][ni] = __builtin_amdgcn_mfma_f32_16x16x32_bf16(
                        a[mi], bfr[ni * 2 + ks], acc[mi][ni], 0, 0, 0);
        }
        if (t < 26) {
            *(short8*)&As[1 - cur][v0 * 72 + c8 * 8] = r0;
            *(short8*)&As[1 - cur][v1 * 72 + c8 * 8] = r1;
            __syncthreads();
        }
    }

    #pragma unroll
    for (int ni = 0; ni < 2; ++ni) {
        const int ch = cb + ni * 16 + lo;
        const float s = g[ch] * (1.0f / sqrtf(va[ch] + EPSf));
        const float sh = bta[ch], mm = mu[ch];
        #pragma unroll
        for (int mi = 0; mi < 4; ++mi)
            #pragma unroll
            for (int j = 0; j < 4; ++j) {
                int vi = mi * 16 + hi * 4 + j;
                if (i0 + vi < n)
                    out[(size_t)s_pos[vi] * 128 + ch] = fmaxf(0.f, fmaf(acc[mi][ni][j] - mm, s, sh));
            }
    }
}

extern "C" void kernel_launch(void* const* d_in, const int* in_sizes, int n_in,
                              void* d_out, int out_size, void* d_ws, size_t ws_size,
                              hipStream_t stream) {
    (void)in_sizes; (void)n_in; (void)ws_size;
    const float* feat   = (const float*)d_in[0];
    const int*   coords = (const int*)d_in[1];
    const float* w1   = (const float*)d_in[2];
    const float* w2   = (const float*)d_in[3];
    const float* wimp = (const float*)d_in[4];
    const float* wf   = (const float*)d_in[5];
    const float* g1 = (const float*)d_in[6],  *b1 = (const float*)d_in[7];
    const float* m1 = (const float*)d_in[8],  *v1 = (const float*)d_in[9];
    const float* g2 = (const float*)d_in[10], *b2 = (const float*)d_in[11];
    const float* m2 = (const float*)d_in[12], *v2 = (const float*)d_in[13];
    const float* g3 = (const float*)d_in[14], *b3 = (const float*)d_in[15];
    const float* m3 = (const float*)d_in[16], *v3 = (const float*)d_in[17];

    char* ws = (char*)d_ws;
    float*    dense16  = (float*)(ws + 0);           //  8,388,608 B (wfb + kb_hi overlay after conv1)
    float*    h1       = (float*)(ws + 8388608);     // 16,777,216 B (h2b overlays after conv2)
    float*    h2       = (float*)(ws + 25165824);    // 33,554,432 B
    uint8_t*  active   = (uint8_t*)(ws + 58720256);  //    131,072 B
    uint8_t*  new_act  = (uint8_t*)(ws + 58851328);  //    131,072 B
    float*    zrow     = (float*)(ws + 58982400);    //        256 B zeros
    int*      count    = (int*)(ws + 58982656);      //        256 B
    const size_t MEMSET_BYTES = 58982912;
    uint32_t* u_logits = (uint32_t*)(ws + 58982912); //    160,000 B
    uint32_t* kb_lo    = (uint32_t*)(ws + 59142912); //    160,000 B
    uint32_t* kth_u    = (uint32_t*)(ws + 59302912); //        256 B
    int*      list     = (int*)(ws + 59303168);      //    524,288 B (act list, then focal list)

    unsigned short* wfb = (unsigned short*)dense16;        // [27][128][64] bf16 (442 KB), after conv1
    uint32_t* kb_hi = (uint32_t*)(ws + 4194304);           // 160 KB inside dead dense16 region
    unsigned short* h2b = (unsigned short*)h1;             // [131072][64] bf16, after conv2

    hipMemsetAsync(d_ws, 0, MEMSET_BYTES, stream);
    hipMemsetAsync(d_out, 0, (size_t)out_size * sizeof(float), stream);

    k_scatter<<<157, 256, 0, stream>>>(feat, coords, dense16, active, new_act);
    k_compact<<<1, 1024, 0, stream>>>(active, list, count);          // ordered active list
    k_conv1<<<dim3(157, 2), 256, 0, stream>>>(list, dense16, w1, g1, b1, m1, v1, h1);
    k_wcvt<<<864, 256, 0, stream>>>(wf, wfb);                        // dense16 now dead
    k_conv2<<<dim3(157, 4), 256, 0, stream>>>(list, h1, w2, g2, b2, m2, v2, h2);
    k_cvt<<<8192, 256, 0, stream>>>(h2, h2b);                        // h1 now dead
    k_imp<<<dim3(157, 2), 256, 0, stream>>>(list, h2, wimp, u_logits, kb_lo, kb_hi);
    k_select<<<2, 256, 0, stream>>>(u_logits, kth_u);
    k_dilate<<<157, 256, 0, stream>>>(list, u_logits, kb_lo, kb_hi, kth_u, new_act);
    k_compact<<<1, 1024, 0, stream>>>(new_act, list, count);         // focal list
    k_focal<<<2048, 256, 0, stream>>>(list, count, h2b, wfb, g3, b3, m3, v3,
                                      (float*)d_out, (const unsigned short*)zrow);
}